// Round 2
// baseline (933.549 us; speedup 1.0000x reference)
//
#include <hip/hip_runtime.h>
#include <stdint.h>

#define N_PTS 200000
#define SITES 131072          // B * 32^3
#define COUTC 256
#define LEAK  0.333f
#define EPSbn 1e-4f

typedef __attribute__((ext_vector_type(8))) short bf16x8;
typedef __attribute__((ext_vector_type(4))) float f32x4;

// ---- helpers -------------------------------------------------------------

__device__ __forceinline__ unsigned short f2bf(float f) {
  union { float f; unsigned u; } un; un.f = f;
  unsigned u = un.u;
  u += 0x7fffu + ((u >> 16) & 1u);   // RNE
  return (unsigned short)(u >> 16);
}

__device__ __forceinline__ float bf2f(unsigned short u) {
  union { unsigned u; float f; } x; x.u = ((unsigned)u) << 16; return x.f;
}

__device__ __forceinline__ void gload_lds16(const void* g, void* l) {
  __builtin_amdgcn_global_load_lds(
      (__attribute__((address_space(1))) void*)(g),
      (__attribute__((address_space(3))) void*)(l), 16, 0, 0);
}

__device__ __forceinline__ void pk_atomic(unsigned short* dst, float lo, float hi) {
  unsigned pk = ((unsigned)f2bf(hi) << 16) | (unsigned)f2bf(lo);
  asm volatile("global_atomic_pk_add_bf16 %0, %1, off"
               :: "v"((unsigned long long)(uintptr_t)dst), "v"(pk) : "memory");
}

// ---- W^T convert: WT[cout][k] = W[k(sub*128+cin)][cout], bf16 ------------

__global__ void wcvt_k(const float* __restrict__ W, unsigned short* __restrict__ WT) {
  int i = blockIdx.x * 256 + threadIdx.x;      // 262144
  int cout = i >> 10, k = i & 1023;
  WT[i] = f2bf(W[k * COUTC + cout]);
}

// ---- feature convert f32 -> bf16, [200000][128] --------------------------

__global__ void fcvt_k(const float* __restrict__ feat, unsigned short* __restrict__ featb) {
  int i = blockIdx.x * 256 + threadIdx.x;      // 3,200,000 exactly
  const float4* f4 = (const float4*)feat;
  float4 a = f4[i * 2], b = f4[i * 2 + 1];
  union { unsigned short u[8]; uint4 v; } r;
  r.u[0] = f2bf(a.x); r.u[1] = f2bf(a.y); r.u[2] = f2bf(a.z); r.u[3] = f2bf(a.w);
  r.u[4] = f2bf(b.x); r.u[5] = f2bf(b.y); r.u[6] = f2bf(b.z); r.u[7] = f2bf(b.w);
  ((uint4*)featb)[i] = r.v;
}

// ---- point prep: site/sub, occupancy, per-sub point lists ----------------

__global__ void pprep_k(const int* __restrict__ coords, const int* __restrict__ bidx,
                        unsigned char* __restrict__ occ, unsigned* __restrict__ psite,
                        unsigned* __restrict__ plist, unsigned* __restrict__ cnt8) {
  int p = blockIdx.x * 256 + threadIdx.x;
  bool ok = p < N_PTS;
  int b = 0, x = 0, y = 0, z = 0;
  if (ok) { b = bidx[p]; x = coords[3 * p]; y = coords[3 * p + 1]; z = coords[3 * p + 2]; }
  unsigned site = b * 32768 + ((x >> 1) << 10) + ((y >> 1) << 5) + (z >> 1);
  int sub = ((x & 1) << 2) | ((y & 1) << 1) | (z & 1);
  if (ok) { occ[site] = 1; psite[p] = site; }
  int lane = threadIdx.x & 63;
  for (int s = 0; s < 8; ++s) {
    unsigned long long m = __ballot(ok && sub == s);
    if (m == 0ull) continue;
    int n = __popcll(m);
    int leader = __ffsll((long long)m) - 1;
    unsigned base = 0;
    if (lane == leader) base = atomicAdd(&cnt8[s], (unsigned)n);
    base = (unsigned)__shfl((int)base, leader);
    unsigned long long lt = m & ((lane == 63) ? 0x7fffffffffffffffull : ((1ull << lane) - 1ull));
    if (ok && sub == s) plist[s * N_PTS + base + __popcll(lt)] = p;
  }
}

// ---- point-GEMM: accum[site][cout] += WT_sub[cout][:] . featb[p][:] ------
// Swapped operands: C rows = couts (4 consecutive per lane) -> pk atomics.
// BM=256 couts, BN=128 points, K=128 (BK=64 x2), 8 waves (4x2).

__global__ __launch_bounds__(512, 1) void pgemm_k(
    const unsigned short* __restrict__ featb, const unsigned short* __restrict__ WT,
    const unsigned* __restrict__ plist, const unsigned* __restrict__ cnt8,
    const unsigned* __restrict__ psite, unsigned short* __restrict__ accum) {
  const int sub = blockIdx.y;
  const unsigned cnt = cnt8[sub];
  const unsigned tile0 = blockIdx.x * 128u;
  if (tile0 >= cnt) return;

  __shared__ __align__(16) char lds[49152];
  __shared__ unsigned pids[128];
  __shared__ unsigned sites[128];
  char* Wlds = lds;            // [256][64] bf16, 32 KB (swizzled)
  char* Flds = lds + 32768;    // [128][64] bf16, 16 KB (swizzled)

  const int tid = threadIdx.x, lane = tid & 63, wid = tid >> 6;
  const int wm = wid >> 1, wn = wid & 1;

  if (tid < 128) {
    unsigned g = tile0 + tid;
    unsigned pid = (g < cnt) ? plist[sub * N_PTS + g] : 0u;
    pids[tid] = pid;
    sites[tid] = psite[pid];
  }
  __syncthreads();

  const char* Wb = (const char*)WT + sub * 256;   // row stride 2048 B (K=1024)

  f32x4 acc[4][4];
#pragma unroll
  for (int m = 0; m < 4; ++m)
#pragma unroll
    for (int n = 0; n < 4; ++n) acc[m][n] = (f32x4){0.f, 0.f, 0.f, 0.f};

  for (int t = 0; t < 2; ++t) {
    // stage W: 2048 16B slots
#pragma unroll
    for (int i = 0; i < 4; ++i) {
      int s = tid + i * 512;
      int row = s >> 3, c = s & 7;
      gload_lds16(Wb + row * 2048 + t * 128 + ((c ^ (row & 7)) << 4), Wlds + (s << 4));
    }
    // stage F (gathered rows): 1024 slots
#pragma unroll
    for (int i = 0; i < 2; ++i) {
      int s = tid + i * 512;
      int row = s >> 3, c = s & 7;
      gload_lds16((const char*)featb + (size_t)pids[row] * 256 + t * 128 + ((c ^ (row & 7)) << 4),
                  Flds + (s << 4));
    }
    __syncthreads();
#pragma unroll
    for (int ks = 0; ks < 2; ++ks) {
      bf16x8 af[4], bfr[4];
#pragma unroll
      for (int m = 0; m < 4; ++m) {
        int row = wm * 64 + m * 16 + (lane & 15);
        int bc = ((ks * 4 + (lane >> 4)) ^ (row & 7)) << 4;
        af[m] = *(const bf16x8*)(Wlds + row * 128 + bc);
      }
#pragma unroll
      for (int n = 0; n < 4; ++n) {
        int row = wn * 64 + n * 16 + (lane & 15);
        int bc = ((ks * 4 + (lane >> 4)) ^ (row & 7)) << 4;
        bfr[n] = *(const bf16x8*)(Flds + row * 128 + bc);
      }
#pragma unroll
      for (int m = 0; m < 4; ++m)
#pragma unroll
        for (int n = 0; n < 4; ++n)
          acc[m][n] = __builtin_amdgcn_mfma_f32_16x16x32_bf16(af[m], bfr[n], acc[m][n], 0, 0, 0);
    }
    __syncthreads();
  }

  // epilogue: pk-atomic into accum[site][cout]; lane holds couts {cout0..cout0+3}
#pragma unroll
  for (int n = 0; n < 4; ++n) {
    int pt = wn * 64 + n * 16 + (lane & 15);
    if (tile0 + pt >= cnt) continue;
    unsigned site = sites[pt];
    unsigned short* rowp = accum + (size_t)site * 256;
#pragma unroll
    for (int m = 0; m < 4; ++m) {
      int cout0 = wm * 64 + m * 16 + ((lane >> 4) << 2);
      pk_atomic(rowp + cout0,     acc[m][n][0], acc[m][n][1]);
      pk_atomic(rowp + cout0 + 2, acc[m][n][2], acc[m][n][3]);
    }
  }
}

// ---- per-channel stats over accum (bias cancels in BN) -------------------

__global__ void stats_k(const unsigned short* __restrict__ accum,
                        const unsigned char* __restrict__ occ, float* __restrict__ st) {
  __shared__ float sA[4][256], sB[4][256];
  int tid = threadIdx.x, lane = tid & 63, w = tid >> 6;
  int base = blockIdx.x * 256;
  float sv[4] = {0, 0, 0, 0}, svv[4] = {0, 0, 0, 0};
  for (int r = w; r < 256; r += 4) {
    const ushort4* row = (const ushort4*)(accum + (size_t)(base + r) * 256);
    ushort4 u = row[lane];
    float v0 = bf2f(u.x), v1 = bf2f(u.y), v2 = bf2f(u.z), v3 = bf2f(u.w);
    sv[0] += v0; svv[0] += v0 * v0;
    sv[1] += v1; svv[1] += v1 * v1;
    sv[2] += v2; svv[2] += v2 * v2;
    sv[3] += v3; svv[3] += v3 * v3;
  }
#pragma unroll
  for (int k = 0; k < 4; ++k) { sA[w][lane * 4 + k] = sv[k]; sB[w][lane * 4 + k] = svv[k]; }
  __syncthreads();
  float a = sA[0][tid] + sA[1][tid] + sA[2][tid] + sA[3][tid];
  float b = sB[0][tid] + sB[1][tid] + sB[2][tid] + sB[3][tid];
  atomicAdd(&st[tid], a);
  atomicAdd(&st[256 + tid], b);
  float c = occ[base + tid] ? 1.0f : 0.0f;
  for (int off = 32; off > 0; off >>= 1) c += __shfl_down(c, off);
  if (lane == 0) atomicAdd(&st[512], c);
}

__global__ void fin_k(const float* __restrict__ gamma, const float* __restrict__ beta,
                      float* __restrict__ st) {
  int t = threadIdx.x;   // 256
  float cnt = st[512];
  float mv = st[t] / cnt;
  float var = st[256 + t] / cnt - mv * mv;
  float sc = rsqrtf(var + EPSbn) * gamma[t];
  st[1024 + t] = sc;
  st[1280 + t] = beta[t] - mv * sc;
}

// ---- BN + LeakyReLU + mask -> f32 out ------------------------------------

__global__ void bn_k(const unsigned short* __restrict__ accum,
                     const unsigned char* __restrict__ occ,
                     const float* __restrict__ st, float* __restrict__ out) {
  const float* sc = st + 1024;
  const float* sh = st + 1280;
  const int total = SITES * 64;
  int stride = gridDim.x * blockDim.x;
  for (int i = blockIdx.x * blockDim.x + threadIdx.x; i < total; i += stride) {
    float4 r;
    if (occ[i >> 6]) {
      int c4 = (i & 63) << 2;
      ushort4 u = ((const ushort4*)accum)[i];
      r.x = fmaf(bf2f(u.x), sc[c4],     sh[c4]);     if (r.x < 0.f) r.x *= LEAK;
      r.y = fmaf(bf2f(u.y), sc[c4 + 1], sh[c4 + 1]); if (r.y < 0.f) r.y *= LEAK;
      r.z = fmaf(bf2f(u.z), sc[c4 + 2], sh[c4 + 2]); if (r.z < 0.f) r.z *= LEAK;
      r.w = fmaf(bf2f(u.w), sc[c4 + 3], sh[c4 + 3]); if (r.w < 0.f) r.w *= LEAK;
    } else {
      r.x = r.y = r.z = r.w = 0.f;
    }
    ((float4*)out)[i] = r;
  }
}

// ---- launch --------------------------------------------------------------

extern "C" void kernel_launch(void* const* d_in, const int* in_sizes, int n_in,
                              void* d_out, int out_size, void* d_ws, size_t ws_size,
                              hipStream_t stream) {
  const float* feat   = (const float*)d_in[0];
  const int*   coords = (const int*)d_in[1];
  const int*   bidx   = (const int*)d_in[2];
  const float* W      = (const float*)d_in[3];
  // d_in[4] = bias: cancelled analytically by BN (per-channel constant)
  const float* gamma  = (const float*)d_in[5];
  const float* beta   = (const float*)d_in[6];
  float* out = (float*)d_out;

  char* ws = (char*)d_ws;
  unsigned short* accum = (unsigned short*)ws;                       // 67,108,864
  unsigned char*  occ   = (unsigned char*)(ws + 67108864);           // 131,072
  unsigned*       cnt8  = (unsigned*)(ws + 67239936);                // 32
  float*          st    = (float*)(ws + 67239968);                   // 8,192
  unsigned short* featb = (unsigned short*)(ws + 67248160);          // 51,200,000
  unsigned short* WT    = (unsigned short*)(ws + 118448160);         // 524,288
  unsigned*       psite = (unsigned*)(ws + 118972448);               // 800,000
  unsigned*       plist = (unsigned*)(ws + 119772448);               // 6,400,000

  hipMemsetAsync(accum, 0, 67108864, stream);
  hipMemsetAsync(occ, 0, 131072 + 32 + 8192, stream);   // occ + cnt8 + st contiguous

  wcvt_k <<<1024,  256, 0, stream>>>(W, WT);
  fcvt_k <<<12500, 256, 0, stream>>>(feat, featb);
  pprep_k<<<782,   256, 0, stream>>>(coords, bidx, occ, psite, plist, cnt8);
  pgemm_k<<<dim3(1563, 8, 1), 512, 0, stream>>>(featb, WT, plist, cnt8, psite, accum);
  stats_k<<<512,   256, 0, stream>>>(accum, occ, st);
  fin_k  <<<1,     256, 0, stream>>>(gamma, beta, st);
  bn_k   <<<2048,  256, 0, stream>>>(accum, occ, st, out);
}

// Round 3
// 487.102 us; speedup vs baseline: 1.9165x; 1.9165x over previous
//
#include <hip/hip_runtime.h>
#include <stdint.h>

#define N_PTS 200000
#define SITES 131072          // B * 32^3
#define COUTC 256
#define LEAK  0.333f
#define EPSbn 1e-4f

typedef __attribute__((ext_vector_type(8))) short bf16x8;
typedef __attribute__((ext_vector_type(4))) float f32x4;

// ---- helpers -------------------------------------------------------------

__device__ __forceinline__ unsigned short f2bf(float f) {
  union { float f; unsigned u; } un; un.f = f;
  unsigned u = un.u;
  u += 0x7fffu + ((u >> 16) & 1u);   // RNE
  return (unsigned short)(u >> 16);
}

__device__ __forceinline__ float bf2f(unsigned short u) {
  union { unsigned u; float f; } x; x.u = ((unsigned)u) << 16; return x.f;
}

__device__ __forceinline__ void gload_lds16(const void* g, void* l) {
  __builtin_amdgcn_global_load_lds(
      (__attribute__((address_space(1))) void*)(g),
      (__attribute__((address_space(3))) void*)(l), 16, 0, 0);
}

// ---- W^T convert: WT[cout][k] = W[k(sub*128+cin)][cout], bf16 ------------

__global__ void wcvt_k(const float* __restrict__ W, unsigned short* __restrict__ WT) {
  int i = blockIdx.x * 256 + threadIdx.x;      // 262144
  int cout = i >> 10, k = i & 1023;
  WT[i] = f2bf(W[k * COUTC + cout]);
}

// ---- point prep: site/sub keys, histogram, sub occupancy mask ------------

__global__ void pprep_k(const int* __restrict__ coords, const int* __restrict__ bidx,
                        unsigned* __restrict__ hist, unsigned* __restrict__ submask,
                        unsigned* __restrict__ psitesub) {
  int p = blockIdx.x * 256 + threadIdx.x;
  if (p >= N_PTS) return;
  int b = bidx[p];
  int x = coords[3 * p], y = coords[3 * p + 1], z = coords[3 * p + 2];
  unsigned site = b * 32768 + ((x >> 1) << 10) + ((y >> 1) << 5) + (z >> 1);
  unsigned sub = ((x & 1) << 2) | ((y & 1) << 1) | (z & 1);
  psitesub[p] = site * 8 + sub;
  atomicAdd(&hist[site], 1u);
  atomicOr(&submask[site], 1u << sub);
}

// ---- 2-level exclusive scan over hist (point offsets) and popc(submask)
//      (voxel ranks), 131072 elements each -------------------------------

__global__ void scan1_k(const unsigned* __restrict__ hist, const unsigned* __restrict__ submask,
                        unsigned* __restrict__ offs, unsigned* __restrict__ srank,
                        unsigned* __restrict__ bsum1, unsigned* __restrict__ bsum2) {
  __shared__ unsigned w1[4], w2[4];
  int t = threadIdx.x, lane = t & 63, w = t >> 6;
  int i = blockIdx.x * 256 + t;
  unsigned v1 = hist[i], v2 = (unsigned)__popc(submask[i]);
  unsigned s1 = v1, s2 = v2;
  for (int d = 1; d < 64; d <<= 1) {
    unsigned n1 = (unsigned)__shfl_up((int)s1, d);
    unsigned n2 = (unsigned)__shfl_up((int)s2, d);
    if (lane >= d) { s1 += n1; s2 += n2; }
  }
  if (lane == 63) { w1[w] = s1; w2[w] = s2; }
  __syncthreads();
  unsigned o1 = 0, o2 = 0;
  for (int k = 0; k < w; ++k) { o1 += w1[k]; o2 += w2[k]; }
  offs[i]  = o1 + s1 - v1;
  srank[i] = o2 + s2 - v2;
  if (t == 255) { bsum1[blockIdx.x] = o1 + s1; bsum2[blockIdx.x] = o2 + s2; }
}

__global__ void scan2_k(const unsigned* __restrict__ bsum1, const unsigned* __restrict__ bsum2,
                        unsigned* __restrict__ boff1, unsigned* __restrict__ boff2) {
  __shared__ unsigned w1[8], w2[8];
  int t = threadIdx.x, lane = t & 63, w = t >> 6;   // 512 threads
  unsigned v1 = bsum1[t], v2 = bsum2[t], s1 = v1, s2 = v2;
  for (int d = 1; d < 64; d <<= 1) {
    unsigned n1 = (unsigned)__shfl_up((int)s1, d);
    unsigned n2 = (unsigned)__shfl_up((int)s2, d);
    if (lane >= d) { s1 += n1; s2 += n2; }
  }
  if (lane == 63) { w1[w] = s1; w2[w] = s2; }
  __syncthreads();
  unsigned o1 = 0, o2 = 0;
  for (int k = 0; k < w; ++k) { o1 += w1[k]; o2 += w2[k]; }
  boff1[t] = o1 + s1 - v1;
  boff2[t] = o2 + s2 - v2;
}

__global__ void scan3_k(unsigned* __restrict__ offs, unsigned* __restrict__ srank,
                        unsigned* __restrict__ cursor,
                        const unsigned* __restrict__ boff1, const unsigned* __restrict__ boff2,
                        const unsigned* __restrict__ submask, float* __restrict__ st) {
  int i = blockIdx.x * 256 + threadIdx.x;
  unsigned o = offs[i] + boff1[blockIdx.x];
  offs[i] = o; cursor[i] = o;
  srank[i] += boff2[blockIdx.x];
  // fold in active-site count
  float c = submask[i] ? 1.0f : 0.0f;
  for (int off = 32; off > 0; off >>= 1) c += __shfl_down(c, off);
  if ((threadIdx.x & 63) == 0) atomicAdd(&st[512], c);
}

__global__ void place_k(const unsigned* __restrict__ psitesub, unsigned* __restrict__ cursor,
                        unsigned* __restrict__ plist) {
  int p = blockIdx.x * 256 + threadIdx.x;
  if (p >= N_PTS) return;
  unsigned ss = psitesub[p];
  unsigned pos = atomicAdd(&cursor[ss >> 3], 1u);
  plist[pos] = ((unsigned)p << 3) | (ss & 7);
}

// ---- gather: one wave per site; sum duplicate-voxel points; write compact
//      bf16 voxel rows [vrank][128] (no atomics) ---------------------------

__global__ __launch_bounds__(512) void gather_k(
    const float* __restrict__ feat, const unsigned* __restrict__ hist,
    const unsigned* __restrict__ offs, const unsigned* __restrict__ plist,
    const unsigned* __restrict__ submask, const unsigned* __restrict__ srank,
    unsigned* __restrict__ gc) {
  int site = blockIdx.x * 8 + (threadIdx.x >> 6);
  int lane = threadIdx.x & 63;
  unsigned n = hist[site];
  if (!n) return;
  unsigned o = offs[site];
  unsigned msk = submask[site], base = srank[site];
  for (unsigned i = 0; i < n; ++i) {
    unsigned e = plist[o + i];
    unsigned sub = e & 7;
    bool owner = true;
    for (unsigned j = 0; j < i; ++j)
      if ((plist[o + j] & 7) == sub) { owner = false; break; }
    if (!owner) continue;
    float2 a = ((const float2*)feat)[(size_t)(e >> 3) * 64 + lane];
    for (unsigned j = i + 1; j < n; ++j) {
      unsigned e2 = plist[o + j];
      if ((e2 & 7) == sub) {
        float2 b2 = ((const float2*)feat)[(size_t)(e2 >> 3) * 64 + lane];
        a.x += b2.x; a.y += b2.y;
      }
    }
    unsigned vr = base + __popc(msk & ((1u << sub) - 1u));
    unsigned pk = ((unsigned)f2bf(a.y) << 16) | (unsigned)f2bf(a.x);
    gc[(size_t)vr * 64 + lane] = pk;
  }
}

// ---- conv GEMM (round-1-verified structure): M=131072 sites, N=256, K=1024
// BM=128, BN=256, BK=64, 8 waves (2x4), 16x16x32 bf16; A staged per-slot with
// compact-voxel redirect (empty -> zero page); bf16 pre-BN out + f32 stats.

__global__ __launch_bounds__(512, 1) void conv_k(
    const unsigned char* __restrict__ gc, const unsigned short* __restrict__ WT,
    const unsigned* __restrict__ submask, const unsigned* __restrict__ srank,
    const unsigned char* __restrict__ zp, unsigned short* __restrict__ accumb,
    float* __restrict__ st) {
  __shared__ __align__(16) char lds[49152];
  char* Alds = lds;              // [128][64] bf16 = 16 KB (swizzled)
  char* Blds = lds + 16384;      // [256][64] bf16 = 32 KB (swizzled)

  const int tid = threadIdx.x;
  const int lane = tid & 63;
  const int wid = tid >> 6;
  const int wm = wid >> 2, wn = wid & 3;
  const int mt = blockIdx.x;

  // hoisted A-row info: each thread owns 2 fixed rows across all t
  const int s0 = tid,        row0 = s0 >> 3, c0 = s0 & 7;
  const int s1 = tid + 512,  row1 = s1 >> 3, c1 = s1 & 7;
  const unsigned m0 = submask[mt * 128 + row0], b0 = srank[mt * 128 + row0];
  const unsigned m1 = submask[mt * 128 + row1], b1 = srank[mt * 128 + row1];
  const char* Bb = (const char*)WT;

  f32x4 acc[4][4];
#pragma unroll
  for (int m = 0; m < 4; ++m)
#pragma unroll
    for (int n = 0; n < 4; ++n) acc[m][n] = (f32x4){0.f, 0.f, 0.f, 0.f};

  for (int t = 0; t < 16; ++t) {
    const int sub = t >> 1, half = (t & 1) * 128;
    {
      unsigned ok = (m0 >> sub) & 1u;
      unsigned vr = b0 + __popc(m0 & ((1u << sub) - 1u));
      const char* src = ok ? (const char*)gc + (size_t)vr * 256 : (const char*)zp;
      gload_lds16(src + half + ((c0 ^ (row0 & 7)) << 4), Alds + (s0 << 4));
    }
    {
      unsigned ok = (m1 >> sub) & 1u;
      unsigned vr = b1 + __popc(m1 & ((1u << sub) - 1u));
      const char* src = ok ? (const char*)gc + (size_t)vr * 256 : (const char*)zp;
      gload_lds16(src + half + ((c1 ^ (row1 & 7)) << 4), Alds + (s1 << 4));
    }
#pragma unroll
    for (int i = 0; i < 4; ++i) {
      int s = tid + i * 512;
      int row = s >> 3, c = s & 7;
      gload_lds16(Bb + row * 2048 + t * 128 + ((c ^ (row & 7)) << 4), Blds + (s << 4));
    }
    __syncthreads();
#pragma unroll
    for (int ks = 0; ks < 2; ++ks) {
      bf16x8 af[4], bfr[4];
#pragma unroll
      for (int m = 0; m < 4; ++m) {
        int row = wm * 64 + m * 16 + (lane & 15);
        int bc = ((ks * 4 + (lane >> 4)) ^ (row & 7)) << 4;
        af[m] = *(const bf16x8*)(Alds + row * 128 + bc);
      }
#pragma unroll
      for (int n = 0; n < 4; ++n) {
        int row = wn * 64 + n * 16 + (lane & 15);
        int bc = ((ks * 4 + (lane >> 4)) ^ (row & 7)) << 4;
        bfr[n] = *(const bf16x8*)(Blds + row * 128 + bc);
      }
#pragma unroll
      for (int m = 0; m < 4; ++m)
#pragma unroll
        for (int n = 0; n < 4; ++n)
          acc[m][n] = __builtin_amdgcn_mfma_f32_16x16x32_bf16(af[m], bfr[n], acc[m][n], 0, 0, 0);
    }
    __syncthreads();
  }

  // epilogue: mask, bf16 pre-BN store, per-channel stats (bias cancels in BN)
  const int colb = wn * 64 + (lane & 15);
  const int rowb = wm * 64 + ((lane >> 4) << 2);
  float mskv[16];
#pragma unroll
  for (int m = 0; m < 4; ++m)
#pragma unroll
    for (int j = 0; j < 4; ++j) {
      int site = mt * 128 + rowb + m * 16 + j;
      mskv[m * 4 + j] = submask[site] ? 1.0f : 0.0f;
    }
  float sv[4] = {0.f, 0.f, 0.f, 0.f}, ssv[4] = {0.f, 0.f, 0.f, 0.f};
#pragma unroll
  for (int n = 0; n < 4; ++n) {
    int cout = colb + n * 16;
#pragma unroll
    for (int m = 0; m < 4; ++m)
#pragma unroll
      for (int j = 0; j < 4; ++j) {
        int site = mt * 128 + rowb + m * 16 + j;
        float v = acc[m][n][j] * mskv[m * 4 + j];
        accumb[(size_t)site * 256 + cout] = f2bf(v);
        sv[n] += v; ssv[n] += v * v;
      }
  }
#pragma unroll
  for (int n = 0; n < 4; ++n) {
    float a = sv[n], b = ssv[n];
    a += __shfl_xor(a, 16); a += __shfl_xor(a, 32);
    b += __shfl_xor(b, 16); b += __shfl_xor(b, 32);
    if (lane < 16) {
      atomicAdd(&st[colb + n * 16], a);
      atomicAdd(&st[256 + colb + n * 16], b);
    }
  }
}

// ---- finalize BN scale/shift ---------------------------------------------

__global__ void fin_k(const float* __restrict__ gamma, const float* __restrict__ beta,
                      float* __restrict__ st) {
  int t = threadIdx.x;   // 256
  float cnt = st[512];
  float mv = st[t] / cnt;
  float var = st[256 + t] / cnt - mv * mv;
  float sc = rsqrtf(var + EPSbn) * gamma[t];
  st[1024 + t] = sc;
  st[1280 + t] = beta[t] - mv * sc;
}

// ---- BN + LeakyReLU + mask -> f32 out ------------------------------------

__global__ void bn_k(const unsigned short* __restrict__ accumb,
                     const unsigned* __restrict__ submask,
                     const float* __restrict__ st, float* __restrict__ out) {
  const float* sc = st + 1024;
  const float* sh = st + 1280;
  const int total = SITES * 64;
  int stride = gridDim.x * blockDim.x;
  for (int i = blockIdx.x * blockDim.x + threadIdx.x; i < total; i += stride) {
    float4 r;
    if (submask[i >> 6]) {
      int c4 = (i & 63) << 2;
      ushort4 u = ((const ushort4*)accumb)[i];
      r.x = fmaf(bf2f(u.x), sc[c4],     sh[c4]);     if (r.x < 0.f) r.x *= LEAK;
      r.y = fmaf(bf2f(u.y), sc[c4 + 1], sh[c4 + 1]); if (r.y < 0.f) r.y *= LEAK;
      r.z = fmaf(bf2f(u.z), sc[c4 + 2], sh[c4 + 2]); if (r.z < 0.f) r.z *= LEAK;
      r.w = fmaf(bf2f(u.w), sc[c4 + 3], sh[c4 + 3]); if (r.w < 0.f) r.w *= LEAK;
    } else {
      r.x = r.y = r.z = r.w = 0.f;
    }
    ((float4*)out)[i] = r;
  }
}

// ---- launch --------------------------------------------------------------

extern "C" void kernel_launch(void* const* d_in, const int* in_sizes, int n_in,
                              void* d_out, int out_size, void* d_ws, size_t ws_size,
                              hipStream_t stream) {
  const float* feat   = (const float*)d_in[0];
  const int*   coords = (const int*)d_in[1];
  const int*   bidx   = (const int*)d_in[2];
  const float* W      = (const float*)d_in[3];
  // d_in[4] = bias: cancelled analytically by BN (per-channel constant)
  const float* gamma  = (const float*)d_in[5];
  const float* beta   = (const float*)d_in[6];
  float* out = (float*)d_out;

  char* ws = (char*)d_ws;
  unsigned*       gc      = (unsigned*)ws;                      // compact voxels 51,200,000
  unsigned short* accumb  = (unsigned short*)(ws + 51200000);   // 67,108,864
  unsigned short* WT      = (unsigned short*)(ws + 118308864);  // 524,288
  unsigned*       hist    = (unsigned*)(ws + 118833152);        // 524,288
  unsigned*       submask = (unsigned*)(ws + 119357440);        // 524,288
  unsigned*       offs    = (unsigned*)(ws + 119881728);        // 524,288
  unsigned*       cursor  = (unsigned*)(ws + 120406016);        // 524,288
  unsigned*       srank   = (unsigned*)(ws + 120930304);        // 524,288
  unsigned*       bsum1   = (unsigned*)(ws + 121454592);        // 2,048
  unsigned*       bsum2   = (unsigned*)(ws + 121456640);        // 2,048
  unsigned*       boff1   = (unsigned*)(ws + 121458688);        // 2,048
  unsigned*       boff2   = (unsigned*)(ws + 121460736);        // 2,048
  unsigned*       psitesub= (unsigned*)(ws + 121462784);        // 800,000
  unsigned*       plist   = (unsigned*)(ws + 122262784);        // 800,000
  float*          st      = (float*)(ws + 123062784);           // 8,192
  unsigned char*  zp      = (unsigned char*)(ws + 123070976);   // 2,048 zero page

  hipMemsetAsync(hist, 0, 1048576, stream);        // hist + submask (contiguous)
  hipMemsetAsync(st, 0, 10240, stream);            // st + zero page (contiguous)

  wcvt_k  <<<1024,  256, 0, stream>>>(W, WT);
  pprep_k <<<782,   256, 0, stream>>>(coords, bidx, hist, submask, psitesub);
  scan1_k <<<512,   256, 0, stream>>>(hist, submask, offs, srank, bsum1, bsum2);
  scan2_k <<<1,     512, 0, stream>>>(bsum1, bsum2, boff1, boff2);
  scan3_k <<<512,   256, 0, stream>>>(offs, srank, cursor, boff1, boff2, submask, st);
  place_k <<<782,   256, 0, stream>>>(psitesub, cursor, plist);
  gather_k<<<16384, 512, 0, stream>>>(feat, hist, offs, plist, submask, srank, gc);
  conv_k  <<<1024,  512, 0, stream>>>((const unsigned char*)gc, WT, submask, srank, zp, accumb, st);
  fin_k   <<<1,     256, 0, stream>>>(gamma, beta, st);
  bn_k    <<<2048,  256, 0, stream>>>(accumb, submask, st, out);
}